// Round 9
// baseline (185.749 us; speedup 1.0000x reference)
//
#include <hip/hip_runtime.h>

#define BB 4
#define SS 16
#define NH 32
#define NKV 8
#define HD 128
#define PAST 8192
#define KVLEN 8208
#define KSPLIT 8
#define ASPLIT 16
#define CHUNK 513   // 16*513 == 8208 exactly
#define NTILE 9

typedef __attribute__((ext_vector_type(8))) short short8;
typedef __attribute__((ext_vector_type(4))) float f32x4;

__device__ __forceinline__ unsigned short f2bf(float f) {
  unsigned u = __float_as_uint(f);
  u = (u + 0x7FFFu + ((u >> 16) & 1u)) >> 16;
  return (unsigned short)u;
}
__device__ __forceinline__ float bf2f(unsigned short h) {
  return __uint_as_float(((unsigned)h) << 16);
}
// packed fp32x2 -> bf16x2 (RNE, identical to f2bf) in one VALU inst
__device__ __forceinline__ unsigned cvtpk(float lo, float hi) {
  unsigned r;
  asm("v_cvt_pk_bf16_f32 %0, %1, %2" : "=v"(r) : "v"(lo), "v"(hi));
  return r;
}
__device__ __forceinline__ void st8(void* p, unsigned lo, unsigned hi) {
  *(unsigned long long*)p = (unsigned long long)lo | ((unsigned long long)hi << 32);
}
__device__ __forceinline__ float getc(const float4& v, int c) {
  return c == 0 ? v.x : c == 1 ? v.y : c == 2 ? v.z : v.w;
}
__device__ __forceinline__ int imin(int a, int b) { return a < b ? a : b; }
__device__ __forceinline__ int imax(int a, int b) { return a > b ? a : b; }

// LDS-ordering barrier that does NOT drain vmcnt.
__device__ __forceinline__ void bar_lds() {
  asm volatile("s_waitcnt lgkmcnt(0)" ::: "memory");
  __builtin_amdgcn_s_barrier();
  asm volatile("" ::: "memory");
}
__device__ __forceinline__ void wait_lds() {
  asm volatile("s_waitcnt lgkmcnt(0)" ::: "memory");
}

// ---------------- hidden_states fp32 -> bf16 ----------------
__global__ __launch_bounds__(256) void xconv(const float* __restrict__ X,
                                             unsigned short* __restrict__ XB) {
  int gid = blockIdx.x * 256 + threadIdx.x;
  float4 v = *(const float4*)&X[(size_t)gid * 4];
  ushort4 pk;
  pk.x = f2bf(v.x); pk.y = f2bf(v.y); pk.z = f2bf(v.z); pk.w = f2bf(v.w);
  *(ushort4*)&XB[(size_t)gid * 4] = pk;
}

// ---------------- skinny GEMM: [64 x K] bf16 @ W(fp32 [K][N]) -> partials ----------------
__global__ __launch_bounds__(256) void gemm_skinny(
    const unsigned short* __restrict__ A,
    const float* __restrict__ W0, const float* __restrict__ W1, const float* __restrict__ W2,
    int nw0, int nw1, int nw2,
    float* __restrict__ part, int Ntot, int kchunk) {
  __shared__ unsigned short Wt[64 * 64];
  const int nt = blockIdx.x, ks = blockIdx.y;
  const int tid = threadIdx.x, lane = tid & 63, w = tid >> 6;
  const int lr = lane & 15, lc = lane >> 4;
  const int n0 = nt * 64;
  const float* W; int wld, wcol;
  if (n0 < nw0) { W = W0; wld = nw0; wcol = n0; }
  else if (n0 < nw0 + nw1) { W = W1; wld = nw1; wcol = n0 - nw0; }
  else { W = W2; wld = nw2; wcol = n0 - nw0 - nw1; }

  f32x4 acc[4];
  #pragma unroll
  for (int mi = 0; mi < 4; ++mi)
    #pragma unroll
    for (int i = 0; i < 4; ++i) acc[mi][i] = 0.f;

  const int qn = tid & 15, qk = tid >> 4;
  const int kb0 = ks * kchunk;
  const int nkt = kchunk / 64;

  float4 wr0, wr1, wr2, wr3;
  {
    const float* wp = &W[(size_t)(kb0 + qk * 4) * wld + wcol + qn * 4];
    wr0 = *(const float4*)(wp);
    wr1 = *(const float4*)(wp + wld);
    wr2 = *(const float4*)(wp + 2 * (size_t)wld);
    wr3 = *(const float4*)(wp + 3 * (size_t)wld);
  }

  for (int kt = 0; kt < nkt; ++kt) {
    const int kb = kb0 + kt * 64;
    #pragma unroll
    for (int c = 0; c < 4; ++c) {
      const int n = qn * 4 + c;
      ushort4 pk;
      pk.x = f2bf(getc(wr0, c)); pk.y = f2bf(getc(wr1, c));
      pk.z = f2bf(getc(wr2, c)); pk.w = f2bf(getc(wr3, c));
      const int byt = n * 128 + ((qk * 8) ^ ((n & 7) << 4));
      *(ushort4*)((char*)Wt + byt) = pk;
    }
    bar_lds();
    if (kt + 1 < nkt) {
      const float* wp = &W[(size_t)(kb + 64 + qk * 4) * wld + wcol + qn * 4];
      wr0 = *(const float4*)(wp);
      wr1 = *(const float4*)(wp + wld);
      wr2 = *(const float4*)(wp + 2 * (size_t)wld);
      wr3 = *(const float4*)(wp + 3 * (size_t)wld);
    }
    #pragma unroll
    for (int kh = 0; kh < 2; ++kh) {
      const int ncol = w * 16 + lr;
      short8 bf = *(const short8*)((char*)Wt + ncol * 128 + ((kh * 64 + lc * 16) ^ ((ncol & 7) << 4)));
      const int kkg = kb + kh * 32 + lc * 8;
      #pragma unroll
      for (int mi = 0; mi < 4; ++mi) {
        short8 af = *(const short8*)&A[(size_t)(mi * 16 + lr) * 4096 + kkg];
        acc[mi] = __builtin_amdgcn_mfma_f32_16x16x32_bf16(af, bf, acc[mi], 0, 0, 0);
      }
    }
    bar_lds();
  }
  #pragma unroll
  for (int mi = 0; mi < 4; ++mi)
    #pragma unroll
    for (int i = 0; i < 4; ++i) {
      const int row = mi * 16 + lc * 4 + i;
      part[((size_t)ks * 64 + row) * Ntot + n0 + w * 16 + lr] = acc[mi][i];
    }
}

// ---------------- reduce proj partials + RoPE -> Qr bf16, K/V-new fp32 ----------------
__global__ __launch_bounds__(256) void proj_reduce(
    const float* __restrict__ part, const int* __restrict__ posids,
    unsigned short* __restrict__ QR, float* __restrict__ KF,
    float* __restrict__ VF) {
  const int gid = blockIdx.x * 256 + threadIdx.x;
  const int j = gid & 63;
  const int hh = (gid >> 6) % 48;
  const int row = gid / 3072;
  const int b = row >> 4, s = row & 15;
  int col0; bool rope;
  if (hh < 32)      { col0 = hh * 128 + j; rope = true; }
  else if (hh < 40) { col0 = 4096 + (hh - 32) * 128 + j; rope = true; }
  else              { col0 = 5120 + (hh - 40) * 128 + j; rope = false; }
  float v0 = 0.f, v1 = 0.f;
  #pragma unroll
  for (int ks = 0; ks < KSPLIT; ++ks) {
    v0 += part[((size_t)ks * 64 + row) * 6144 + col0];
    v1 += part[((size_t)ks * 64 + row) * 6144 + col0 + 64];
  }
  float o0 = v0, o1 = v1;
  if (rope) {
    const int pos = posids[row];
    const double inv = exp2(-(double)j * (13.287712379549449 / 64.0));
    double th = (double)pos * inv;
    const double TWO_PI = 6.283185307179586476925286766559;
    th -= floor(th / TWO_PI) * TWO_PI;
    float sv, cv;
    sincosf((float)th, &sv, &cv);
    o0 = v0 * cv - v1 * sv;
    o1 = v1 * cv + v0 * sv;
  }
  if (hh < 32) {
    const size_t didx = (((size_t)(b * 32 + hh) * 16 + s) * 128) + j;
    QR[didx] = f2bf(o0);
    QR[didx + 64] = f2bf(o1);
  } else if (hh < 40) {
    const size_t didx = (((size_t)(b * 8 + (hh - 32)) * 16 + s) * 128) + j;
    KF[didx] = o0;
    KF[didx + 64] = o1;
  } else {
    const size_t didx = (((size_t)(b * 8 + (hh - 40)) * 16 + s) * 128) + j;
    VF[didx] = o0;
    VF[didx + 64] = o1;
  }
}

// ---------------- flash attention: wave-specialized, deep producer pipeline ----------------
// Waves 0-3 consumers (setprio 1), waves 4-7 producers. Producer K-tiles are
// register-ping-ponged ACROSS tile-steps: K(t+2) is issued before the step-t
// barrier and written at step t+1 -- a load cannot be sunk across an
// asm("memory") barrier, so this live range is structurally un-collapsible
// and K loads get a full tile-step (+queue) of flight. V(t+1) is issued at
// the top of step t and written at the bottom (T14 split). The compiler's
// auto-waitcnt becomes a counted vmcnt (16/8), never draining the newer
// loads -- the T3/T4 pattern, generated from plain HIP.
__global__ __launch_bounds__(512, 4) void attn_kernel(
    const float* __restrict__ kc, const float* __restrict__ vc,
    const unsigned short* __restrict__ QR, const float* __restrict__ KF,
    const float* __restrict__ VF,
    float* __restrict__ Opart, float* __restrict__ ML) {
  __shared__ unsigned short Klds[2][64 * 136];  // [key][128d], row 272B (pad 8)
  __shared__ unsigned short Vt[2][128 * 64];    // [d][64key], XOR swizzle g(d)
  __shared__ unsigned short Plds[4][16 * 72];   // per-consumer-wave P

  const int split = blockIdx.x, kvh = blockIdx.y, b = blockIdx.z;
  const int tid = threadIdx.x;
  const int kstart = split * CHUNK;

  if (tid >= 256) {
    // ================= PRODUCER: 4 waves stage K/V tiles =================
    const int ptid = tid - 256;
    const int dl = (ptid & 31) * 4;   // d-offset (floats)
    const int rk = ptid >> 5;         // row-group 0..7
    const float* kc_base = kc + (((size_t)b * PAST) * NKV + kvh) * HD + dl;
    const float* vc_base = vc + (((size_t)b * PAST) * NKV + kvh) * HD + dl;
    const float* kf_base = KF + (((size_t)b * NKV + kvh) * SS) * HD + dl;
    const float* vf_base = VF + (((size_t)b * NKV + kvh) * SS) * HD + dl;

    float4 kpA[8], kpB[8], vp[8];

    auto issue_K = [&](int kk0, float4* dst) {
      #pragma unroll
      for (int pass = 0; pass < 8; ++pass) {
        const int kk = kk0 + pass * 8 + rk;
        const int ts = imin(imax(kk - PAST, 0), SS - 1);
        const float* p = (kk < PAST) ? (kc_base + (size_t)kk * (NKV * HD))
                                     : (kf_base + (size_t)ts * HD);
        dst[pass] = *(const float4*)p;
      }
    };
    auto issue_V = [&](int kk0) {
      #pragma unroll
      for (int j = 0; j < 8; ++j) {
        const int kk = kk0 + rk * 8 + j;
        const int ts = imin(imax(kk - PAST, 0), SS - 1);
        const float* p = (kk < PAST) ? (vc_base + (size_t)kk * (NKV * HD))
                                     : (vf_base + (size_t)ts * HD);
        vp[j] = *(const float4*)p;
      }
    };
    auto write_K = [&](const float4* src, int buf) {
      #pragma unroll
      for (int pass = 0; pass < 8; ++pass) {
        const int kr = pass * 8 + rk;
        st8((char*)&Klds[buf][0] + kr * 272 + dl * 2,
            cvtpk(src[pass].x, src[pass].y), cvtpk(src[pass].z, src[pass].w));
      }
    };
    auto write_V = [&](int buf) {
      #pragma unroll
      for (int pp = 0; pp < 2; ++pp) {
        const int krb = rk * 8 + pp * 4;
        #pragma unroll
        for (int c = 0; c < 4; ++c) {
          const int d = dl + c;
          const int g = ((d ^ (d >> 3)) & 7) << 4;
          st8((char*)&Vt[buf][0] + d * 128 + ((krb * 2) ^ g),
              cvtpk(getc(vp[pp * 4 + 0], c), getc(vp[pp * 4 + 1], c)),
              cvtpk(getc(vp[pp * 4 + 2], c), getc(vp[pp * 4 + 3], c)));
        }
      }
    };

    // prologue: tile0 -> buf0 (via kpA); K(1) -> kpB stays in flight across B0
    issue_K(kstart, kpA);
    issue_V(kstart);
    write_K(kpA, 0);          // waits kpA (vmcnt leaves V0 outstanding)
    write_V(0);               // waits V0
    issue_K(kstart + 64, kpB);
    bar_lds();                // B0: tile 0 ready; K(1) in flight

    for (int t = 0; t < NTILE; ++t) {
      const bool haveN = (t + 1 < NTILE);
      if (haveN) issue_V(kstart + (t + 1) * 64);              // V(t+1): in-step flight
      if (t + 2 < NTILE) {                                    // K(t+2): cross-step flight
        if ((t & 1) == 0) issue_K(kstart + (t + 2) * 64, kpA);
        else              issue_K(kstart + (t + 2) * 64, kpB);
      }
      if (haveN) {
        if ((t & 1) == 0) write_K(kpB, (t + 1) & 1);          // K(t+1) landed ~1 step ago
        else              write_K(kpA, (t + 1) & 1);
        write_V((t + 1) & 1);                                 // waits V(t+1) only
      }
      bar_lds();              // B_{t+1}: tile t+1 staged; K(t+2) still in flight
    }
    // producers exit
  } else {
    // ================= CONSUMER: 4 waves, one head each =================
    __builtin_amdgcn_s_setprio(1);   // T5: favor consumer issue vs producer waves
    const int lane = tid & 63, w = tid >> 6;
    const int lr = lane & 15, lc = lane >> 4;

    short8 qf[4];
    {
      const unsigned short* qb = QR + (((size_t)b * NH + kvh * 4 + w) * SS + lr) * HD;
      #pragma unroll
      for (int kd = 0; kd < 4; ++kd) qf[kd] = *(const short8*)(qb + kd * 32 + lc * 8);
    }

    float m_i[4], l_i[4];
    f32x4 oacc[8];
    #pragma unroll
    for (int i = 0; i < 4; ++i) { m_i[i] = -1e30f; l_i[i] = 0.f; }
    #pragma unroll
    for (int d8 = 0; d8 < 8; ++d8)
      #pragma unroll
      for (int i = 0; i < 4; ++i) oacc[d8][i] = 0.f;

    bar_lds();                               // B0: wait tile 0

    for (int t = 0; t < NTILE; ++t) {
      const int buf = t & 1;
      const int kk0 = kstart + t * 64;
      const int nvalid = imin(64, kstart + CHUNK - kk0);

      // ---- QK^T ----
      f32x4 sacc[4];
      #pragma unroll
      for (int nb = 0; nb < 4; ++nb)
        #pragma unroll
        for (int i = 0; i < 4; ++i) sacc[nb][i] = 0.f;
      #pragma unroll
      for (int kd = 0; kd < 4; ++kd) {
        #pragma unroll
        for (int nb = 0; nb < 4; ++nb) {
          const int key = nb * 16 + lr;
          short8 bf = *(const short8*)((char*)&Klds[buf][0] + key * 272 + kd * 64 + lc * 16);
          sacc[nb] = __builtin_amdgcn_mfma_f32_16x16x32_bf16(qf[kd], bf, sacc[nb], 0, 0, 0);
        }
      }

      // ---- online softmax (row s = lc*4+i, key col = nb*16+lr) ----
      const float scl = 0.08838834764831845f;
      float resc[4];
      #pragma unroll
      for (int i = 0; i < 4; ++i) {
        const int s = lc * 4 + i;
        float vv[4];
        #pragma unroll
        for (int nb = 0; nb < 4; ++nb) {
          const int klocal = nb * 16 + lr;
          const int kk = kk0 + klocal;
          const bool ok = (klocal < nvalid) && (kk <= PAST + s);
          vv[nb] = ok ? sacc[nb][i] * scl : -1e30f;
        }
        float mx = fmaxf(fmaxf(vv[0], vv[1]), fmaxf(vv[2], vv[3]));
        mx = fmaxf(mx, __shfl_xor(mx, 1));
        mx = fmaxf(mx, __shfl_xor(mx, 2));
        mx = fmaxf(mx, __shfl_xor(mx, 4));
        mx = fmaxf(mx, __shfl_xor(mx, 8));
        const float mnew = fmaxf(m_i[i], mx);
        const float rs = __expf(m_i[i] - mnew);
        float p0 = __expf(vv[0] - mnew), p1 = __expf(vv[1] - mnew);
        float p2 = __expf(vv[2] - mnew), p3 = __expf(vv[3] - mnew);
        float sum = p0 + p1 + p2 + p3;
        sum += __shfl_xor(sum, 1);
        sum += __shfl_xor(sum, 2);
        sum += __shfl_xor(sum, 4);
        sum += __shfl_xor(sum, 8);
        l_i[i] = l_i[i] * rs + sum;
        m_i[i] = mnew;
        resc[i] = rs;
        unsigned short* prow = &Plds[w][s * 72];
        prow[0 * 16 + lr] = f2bf(p0);
        prow[1 * 16 + lr] = f2bf(p1);
        prow[2 * 16 + lr] = f2bf(p2);
        prow[3 * 16 + lr] = f2bf(p3);
      }
      #pragma unroll
      for (int d8 = 0; d8 < 8; ++d8)
        #pragma unroll
        for (int i = 0; i < 4; ++i) oacc[d8][i] *= resc[i];

      wait_lds();  // Plds[w] is wave-private: DS-retire only

      // ---- PV ----
      #pragma unroll
      for (int ks2 = 0; ks2 < 2; ++ks2) {
        short8 pf = *(const short8*)((char*)&Plds[w][0] + lr * 144 + ks2 * 64 + lc * 16);
        #pragma unroll
        for (int db = 0; db < 8; ++db) {
          const int d = db * 16 + lr;
          const int g = ((d ^ (d >> 3)) & 7) << 4;
          short8 vf = *(const short8*)((char*)&Vt[buf][0] + d * 128 + ((ks2 * 64 + lc * 16) ^ g));
          oacc[db] = __builtin_amdgcn_mfma_f32_16x16x32_bf16(pf, vf, oacc[db], 0, 0, 0);
        }
      }

      bar_lds();                             // B_{t+1}: tile t+1 staged
    }

    // ---- epilogue: partial O, m, l ----
    const size_t pbase = (((size_t)b * NKV + kvh) * ASPLIT + split) * 64;
    #pragma unroll
    for (int db = 0; db < 8; ++db)
      #pragma unroll
      for (int i = 0; i < 4; ++i) {
        const int row = w * 16 + lc * 4 + i;
        Opart[(pbase + row) * HD + db * 16 + lr] = oacc[db][i];
      }
    if (lr == 0) {
      #pragma unroll
      for (int i = 0; i < 4; ++i) {
        const int row = w * 16 + lc * 4 + i;
        ML[(pbase + row) * 2] = m_i[i];
        ML[(pbase + row) * 2 + 1] = l_i[i];
      }
    }
  }
}

// ---------------- combine split-softmax partials -> attn bf16 [64][4096] ----------------
__global__ __launch_bounds__(128) void combine(const float* __restrict__ Opart,
                                               const float* __restrict__ ML,
                                               unsigned short* __restrict__ AT) {
  const int rid = blockIdx.x;
  const int d = threadIdx.x;
  const int s = rid & 15, h = (rid >> 4) & 31, b = rid >> 9;
  const int kvh = h >> 2, g = h & 3;
  const int prow = g * 16 + s;
  const size_t base = ((size_t)b * NKV + kvh) * ASPLIT;
  float ms[ASPLIT], ls[ASPLIT];
  float M = -1e30f;
  #pragma unroll
  for (int sp = 0; sp < ASPLIT; ++sp) {
    ms[sp] = ML[((base + sp) * 64 + prow) * 2];
    ls[sp] = ML[((base + sp) * 64 + prow) * 2 + 1];
    M = fmaxf(M, ms[sp]);
  }
  float denom = 0.f, acc = 0.f;
  #pragma unroll
  for (int sp = 0; sp < ASPLIT; ++sp) {
    const float e = __expf(ms[sp] - M);
    denom += ls[sp] * e;
    acc += e * Opart[((base + sp) * 64 + prow) * HD + d];
  }
  AT[((size_t)(b * 16 + s)) * 4096 + h * 128 + d] = f2bf(acc / denom);
}

// ---------------- reduce Wo partials -> fp32 out ----------------
__global__ __launch_bounds__(256) void wo_reduce(const float* __restrict__ part,
                                                 float* __restrict__ out) {
  const int gid = blockIdx.x * 256 + threadIdx.x;
  float4 s = {0, 0, 0, 0};
  #pragma unroll
  for (int ks = 0; ks < KSPLIT; ++ks) {
    const float4 v = *(const float4*)&part[(size_t)ks * 262144 + (size_t)gid * 4];
    s.x += v.x; s.y += v.y; s.z += v.z; s.w += v.w;
  }
  *(float4*)&out[(size_t)gid * 4] = s;
}

extern "C" void kernel_launch(void* const* d_in, const int* in_sizes, int n_in,
                              void* d_out, int out_size, void* d_ws, size_t ws_size,
                              hipStream_t stream) {
  (void)in_sizes; (void)n_in; (void)out_size; (void)ws_size;
  const float* hs = (const float*)d_in[0];
  const float* kc = (const float*)d_in[1];
  const float* vc = (const float*)d_in[2];
  const float* Wq = (const float*)d_in[3];
  const float* Wk = (const float*)d_in[4];
  const float* Wv = (const float*)d_in[5];
  const float* Wo = (const float*)d_in[6];
  const int* pos = (const int*)d_in[7];
  float* out = (float*)d_out;
  char* ws = (char*)d_ws;

  unsigned short* XB = (unsigned short*)(ws);              // 512 KB
  unsigned short* QR = (unsigned short*)(ws + 0x080000);   // 512 KB
  float* KF = (float*)(ws + 0x100000);                     // 256 KB fp32 new-K
  float* VF = (float*)(ws + 0x140000);                     // 256 KB fp32 new-V
  unsigned short* AT = (unsigned short*)(ws + 0x180000);   // 512 KB
  float* RED = (float*)(ws + 0x200000);                    // gemm partials / Opart (17 MB)
  float* ML  = (float*)(ws + 0x1300000);                   // 256 KB

  hipLaunchKernelGGL(xconv, dim3(256), dim3(256), 0, stream, hs, XB);
  hipLaunchKernelGGL(gemm_skinny, dim3(96, KSPLIT), dim3(256), 0, stream,
                     XB, Wq, Wk, Wv, 4096, 1024, 1024, RED, 6144, 4096 / KSPLIT);
  hipLaunchKernelGGL(proj_reduce, dim3(768), dim3(256), 0, stream, RED, pos, QR, KF, VF);
  hipLaunchKernelGGL(attn_kernel, dim3(ASPLIT, NKV, BB), dim3(512), 0, stream,
                     kc, vc, QR, KF, VF, RED, ML);
  hipLaunchKernelGGL(combine, dim3(2048), dim3(128), 0, stream, RED, ML, AT);
  hipLaunchKernelGGL(gemm_skinny, dim3(64, KSPLIT), dim3(256), 0, stream,
                     AT, Wo, Wo, Wo, 4096, 0, 0, RED, 4096, 4096 / KSPLIT);
  hipLaunchKernelGGL(wo_reduce, dim3(256), dim3(256), 0, stream, RED, out);
}

// Round 10
// 134.963 us; speedup vs baseline: 1.3763x; 1.3763x over previous
//
#include <hip/hip_runtime.h>

#define BB 4
#define SS 16
#define NH 32
#define NKV 8
#define HD 128
#define PAST 8192
#define KVLEN 8208
#define KSPLIT 8
#define ASPLIT 16
#define CHUNK 513   // 16*513 == 8208 exactly
#define NTILE 9

typedef __attribute__((ext_vector_type(8))) short short8;
typedef __attribute__((ext_vector_type(4))) float f32x4;

__device__ __forceinline__ unsigned short f2bf(float f) {
  unsigned u = __float_as_uint(f);
  u = (u + 0x7FFFu + ((u >> 16) & 1u)) >> 16;
  return (unsigned short)u;
}
__device__ __forceinline__ float bf2f(unsigned short h) {
  return __uint_as_float(((unsigned)h) << 16);
}
// packed fp32x2 -> bf16x2 (RNE, identical to f2bf) in one VALU inst
__device__ __forceinline__ unsigned cvtpk(float lo, float hi) {
  unsigned r;
  asm("v_cvt_pk_bf16_f32 %0, %1, %2" : "=v"(r) : "v"(lo), "v"(hi));
  return r;
}
__device__ __forceinline__ void st8(void* p, unsigned lo, unsigned hi) {
  *(unsigned long long*)p = (unsigned long long)lo | ((unsigned long long)hi << 32);
}
__device__ __forceinline__ float getc(const float4& v, int c) {
  return c == 0 ? v.x : c == 1 ? v.y : c == 2 ? v.z : v.w;
}
__device__ __forceinline__ int imin(int a, int b) { return a < b ? a : b; }
__device__ __forceinline__ int imax(int a, int b) { return a > b ? a : b; }

// LDS-ordering barrier that does NOT drain vmcnt.
__device__ __forceinline__ void bar_lds() {
  asm volatile("s_waitcnt lgkmcnt(0)" ::: "memory");
  __builtin_amdgcn_s_barrier();
  asm volatile("" ::: "memory");
}
__device__ __forceinline__ void wait_lds() {
  asm volatile("s_waitcnt lgkmcnt(0)" ::: "memory");
}

// ---------------- hidden_states fp32 -> bf16 ----------------
__global__ __launch_bounds__(256) void xconv(const float* __restrict__ X,
                                             unsigned short* __restrict__ XB) {
  int gid = blockIdx.x * 256 + threadIdx.x;
  float4 v = *(const float4*)&X[(size_t)gid * 4];
  ushort4 pk;
  pk.x = f2bf(v.x); pk.y = f2bf(v.y); pk.z = f2bf(v.z); pk.w = f2bf(v.w);
  *(ushort4*)&XB[(size_t)gid * 4] = pk;
}

// ---------------- skinny GEMM: [64 x K] bf16 @ W(fp32 [K][N]) -> partials ----------------
__global__ __launch_bounds__(256) void gemm_skinny(
    const unsigned short* __restrict__ A,
    const float* __restrict__ W0, const float* __restrict__ W1, const float* __restrict__ W2,
    int nw0, int nw1, int nw2,
    float* __restrict__ part, int Ntot, int kchunk) {
  __shared__ unsigned short Wt[64 * 64];
  const int nt = blockIdx.x, ks = blockIdx.y;
  const int tid = threadIdx.x, lane = tid & 63, w = tid >> 6;
  const int lr = lane & 15, lc = lane >> 4;
  const int n0 = nt * 64;
  const float* W; int wld, wcol;
  if (n0 < nw0) { W = W0; wld = nw0; wcol = n0; }
  else if (n0 < nw0 + nw1) { W = W1; wld = nw1; wcol = n0 - nw0; }
  else { W = W2; wld = nw2; wcol = n0 - nw0 - nw1; }

  f32x4 acc[4];
  #pragma unroll
  for (int mi = 0; mi < 4; ++mi)
    #pragma unroll
    for (int i = 0; i < 4; ++i) acc[mi][i] = 0.f;

  const int qn = tid & 15, qk = tid >> 4;
  const int kb0 = ks * kchunk;
  const int nkt = kchunk / 64;

  float4 wr0, wr1, wr2, wr3;
  {
    const float* wp = &W[(size_t)(kb0 + qk * 4) * wld + wcol + qn * 4];
    wr0 = *(const float4*)(wp);
    wr1 = *(const float4*)(wp + wld);
    wr2 = *(const float4*)(wp + 2 * (size_t)wld);
    wr3 = *(const float4*)(wp + 3 * (size_t)wld);
  }

  for (int kt = 0; kt < nkt; ++kt) {
    const int kb = kb0 + kt * 64;
    #pragma unroll
    for (int c = 0; c < 4; ++c) {
      const int n = qn * 4 + c;
      ushort4 pk;
      pk.x = f2bf(getc(wr0, c)); pk.y = f2bf(getc(wr1, c));
      pk.z = f2bf(getc(wr2, c)); pk.w = f2bf(getc(wr3, c));
      const int byt = n * 128 + ((qk * 8) ^ ((n & 7) << 4));
      *(ushort4*)((char*)Wt + byt) = pk;
    }
    bar_lds();
    if (kt + 1 < nkt) {
      const float* wp = &W[(size_t)(kb + 64 + qk * 4) * wld + wcol + qn * 4];
      wr0 = *(const float4*)(wp);
      wr1 = *(const float4*)(wp + wld);
      wr2 = *(const float4*)(wp + 2 * (size_t)wld);
      wr3 = *(const float4*)(wp + 3 * (size_t)wld);
    }
    #pragma unroll
    for (int kh = 0; kh < 2; ++kh) {
      const int ncol = w * 16 + lr;
      short8 bf = *(const short8*)((char*)Wt + ncol * 128 + ((kh * 64 + lc * 16) ^ ((ncol & 7) << 4)));
      const int kkg = kb + kh * 32 + lc * 8;
      #pragma unroll
      for (int mi = 0; mi < 4; ++mi) {
        short8 af = *(const short8*)&A[(size_t)(mi * 16 + lr) * 4096 + kkg];
        acc[mi] = __builtin_amdgcn_mfma_f32_16x16x32_bf16(af, bf, acc[mi], 0, 0, 0);
      }
    }
    bar_lds();
  }
  #pragma unroll
  for (int mi = 0; mi < 4; ++mi)
    #pragma unroll
    for (int i = 0; i < 4; ++i) {
      const int row = mi * 16 + lc * 4 + i;
      part[((size_t)ks * 64 + row) * Ntot + n0 + w * 16 + lr] = acc[mi][i];
    }
}

// ---------------- reduce proj partials + RoPE -> Qr bf16, K/V-new fp32 ----------------
__global__ __launch_bounds__(256) void proj_reduce(
    const float* __restrict__ part, const int* __restrict__ posids,
    unsigned short* __restrict__ QR, float* __restrict__ KF,
    float* __restrict__ VF) {
  const int gid = blockIdx.x * 256 + threadIdx.x;
  const int j = gid & 63;
  const int hh = (gid >> 6) % 48;
  const int row = gid / 3072;
  const int b = row >> 4, s = row & 15;
  int col0; bool rope;
  if (hh < 32)      { col0 = hh * 128 + j; rope = true; }
  else if (hh < 40) { col0 = 4096 + (hh - 32) * 128 + j; rope = true; }
  else              { col0 = 5120 + (hh - 40) * 128 + j; rope = false; }
  float v0 = 0.f, v1 = 0.f;
  #pragma unroll
  for (int ks = 0; ks < KSPLIT; ++ks) {
    v0 += part[((size_t)ks * 64 + row) * 6144 + col0];
    v1 += part[((size_t)ks * 64 + row) * 6144 + col0 + 64];
  }
  float o0 = v0, o1 = v1;
  if (rope) {
    const int pos = posids[row];
    const double inv = exp2(-(double)j * (13.287712379549449 / 64.0));
    double th = (double)pos * inv;
    const double TWO_PI = 6.283185307179586476925286766559;
    th -= floor(th / TWO_PI) * TWO_PI;
    float sv, cv;
    sincosf((float)th, &sv, &cv);
    o0 = v0 * cv - v1 * sv;
    o1 = v1 * cv + v0 * sv;
  }
  if (hh < 32) {
    const size_t didx = (((size_t)(b * 32 + hh) * 16 + s) * 128) + j;
    QR[didx] = f2bf(o0);
    QR[didx + 64] = f2bf(o1);
  } else if (hh < 40) {
    const size_t didx = (((size_t)(b * 8 + (hh - 32)) * 16 + s) * 128) + j;
    KF[didx] = o0;
    KF[didx + 64] = o1;
  } else {
    const size_t didx = (((size_t)(b * 8 + (hh - 40)) * 16 + s) * 128) + j;
    VF[didx] = o0;
    VF[didx + 64] = o1;
  }
}

// ---------------- flash attention: wave-specialized producer/consumer ----------------
// R8 body unchanged. ONLY change: block->work mapping. KV layout [b,kk,nkv,hd]
// means the 8 kvh rows of one key are CONTIGUOUS (one 4KB DRAM page); blocks
// sharing a key range (all kvh x b, 32 blocks) are now CONSECUTIVE in
// blockIdx (x = kvh + 8*b, y = split), so they run concurrently in lockstep
// and their same-page requests co-occur -> DRAM page hits instead of 1/8-page
// activations. No change to per-block work/LDS/regs.
__global__ __launch_bounds__(512, 2) void attn_kernel(
    const float* __restrict__ kc, const float* __restrict__ vc,
    const unsigned short* __restrict__ QR, const float* __restrict__ KF,
    const float* __restrict__ VF,
    float* __restrict__ Opart, float* __restrict__ ML) {
  __shared__ unsigned short Klds[2][64 * 136];  // [key][128d], row 272B (pad 8)
  __shared__ unsigned short Vt[2][128 * 64];    // [d][64key], XOR swizzle g(d)
  __shared__ unsigned short Plds[4][16 * 72];   // per-consumer-wave P

  const int kvh = blockIdx.x & 7, b = blockIdx.x >> 3;  // 32 consecutive blocks
  const int split = blockIdx.y;                         // share one key range
  const int tid = threadIdx.x;
  const int kstart = split * CHUNK;

  if (tid >= 256) {
    // ================= PRODUCER: 4 waves stage K/V tiles =================
    const int ptid = tid - 256;
    const int dl = (ptid & 31) * 4;   // d-offset (floats)
    const int rk = ptid >> 5;         // row-group 0..7
    const float* kc_base = kc + (((size_t)b * PAST) * NKV + kvh) * HD + dl;
    const float* vc_base = vc + (((size_t)b * PAST) * NKV + kvh) * HD + dl;
    const float* kf_base = KF + (((size_t)b * NKV + kvh) * SS) * HD + dl;
    const float* vf_base = VF + (((size_t)b * NKV + kvh) * SS) * HD + dl;

    auto stage = [&](int kk0, int buf) {
      float4 kpre[8];   // K rows pass*8+rk
      float4 vpre[8];   // V rows rk*8+j
      #pragma unroll
      for (int pass = 0; pass < 8; ++pass) {
        const int kk = kk0 + pass * 8 + rk;
        const int ts = imin(imax(kk - PAST, 0), SS - 1);
        const float* p = (kk < PAST) ? (kc_base + (size_t)kk * (NKV * HD))
                                     : (kf_base + (size_t)ts * HD);
        kpre[pass] = *(const float4*)p;
      }
      #pragma unroll
      for (int j = 0; j < 8; ++j) {
        const int kk = kk0 + rk * 8 + j;
        const int ts = imin(imax(kk - PAST, 0), SS - 1);
        const float* p = (kk < PAST) ? (vc_base + (size_t)kk * (NKV * HD))
                                     : (vf_base + (size_t)ts * HD);
        vpre[j] = *(const float4*)p;
      }
      #pragma unroll
      for (int pass = 0; pass < 8; ++pass) {
        const int kr = pass * 8 + rk;
        st8((char*)&Klds[buf][0] + kr * 272 + dl * 2,
            cvtpk(kpre[pass].x, kpre[pass].y), cvtpk(kpre[pass].z, kpre[pass].w));
      }
      #pragma unroll
      for (int pp = 0; pp < 2; ++pp) {
        const int krb = rk * 8 + pp * 4;
        #pragma unroll
        for (int c = 0; c < 4; ++c) {
          const int d = dl + c;
          const int g = ((d ^ (d >> 3)) & 7) << 4;
          st8((char*)&Vt[buf][0] + d * 128 + ((krb * 2) ^ g),
              cvtpk(getc(vpre[pp * 4 + 0], c), getc(vpre[pp * 4 + 1], c)),
              cvtpk(getc(vpre[pp * 4 + 2], c), getc(vpre[pp * 4 + 3], c)));
        }
      }
    };

    stage(kstart, 0);
    bar_lds();                               // B0: tile 0 ready
    for (int t = 0; t < NTILE; ++t) {
      if (t + 1 < NTILE) stage(kstart + (t + 1) * 64, (t + 1) & 1);
      bar_lds();                             // B_{t+1}
    }
    // producers exit; no barriers after this point anywhere
  } else {
    // ================= CONSUMER: 4 waves, one head each =================
    const int lane = tid & 63, w = tid >> 6;
    const int lr = lane & 15, lc = lane >> 4;

    short8 qf[4];
    {
      const unsigned short* qb = QR + (((size_t)b * NH + kvh * 4 + w) * SS + lr) * HD;
      #pragma unroll
      for (int kd = 0; kd < 4; ++kd) qf[kd] = *(const short8*)(qb + kd * 32 + lc * 8);
    }

    float m_i[4], l_i[4];
    f32x4 oacc[8];
    #pragma unroll
    for (int i = 0; i < 4; ++i) { m_i[i] = -1e30f; l_i[i] = 0.f; }
    #pragma unroll
    for (int d8 = 0; d8 < 8; ++d8)
      #pragma unroll
      for (int i = 0; i < 4; ++i) oacc[d8][i] = 0.f;

    bar_lds();                               // B0: wait tile 0

    for (int t = 0; t < NTILE; ++t) {
      const int buf = t & 1;
      const int kk0 = kstart + t * 64;
      const int nvalid = imin(64, kstart + CHUNK - kk0);

      // ---- QK^T ----
      f32x4 sacc[4];
      #pragma unroll
      for (int nb = 0; nb < 4; ++nb)
        #pragma unroll
        for (int i = 0; i < 4; ++i) sacc[nb][i] = 0.f;
      #pragma unroll
      for (int kd = 0; kd < 4; ++kd) {
        #pragma unroll
        for (int nb = 0; nb < 4; ++nb) {
          const int key = nb * 16 + lr;
          short8 bf = *(const short8*)((char*)&Klds[buf][0] + key * 272 + kd * 64 + lc * 16);
          sacc[nb] = __builtin_amdgcn_mfma_f32_16x16x32_bf16(qf[kd], bf, sacc[nb], 0, 0, 0);
        }
      }

      // ---- online softmax (row s = lc*4+i, key col = nb*16+lr) ----
      const float scl = 0.08838834764831845f;
      float resc[4];
      #pragma unroll
      for (int i = 0; i < 4; ++i) {
        const int s = lc * 4 + i;
        float vv[4];
        #pragma unroll
        for (int nb = 0; nb < 4; ++nb) {
          const int klocal = nb * 16 + lr;
          const int kk = kk0 + klocal;
          const bool ok = (klocal < nvalid) && (kk <= PAST + s);
          vv[nb] = ok ? sacc[nb][i] * scl : -1e30f;
        }
        float mx = fmaxf(fmaxf(vv[0], vv[1]), fmaxf(vv[2], vv[3]));
        mx = fmaxf(mx, __shfl_xor(mx, 1));
        mx = fmaxf(mx, __shfl_xor(mx, 2));
        mx = fmaxf(mx, __shfl_xor(mx, 4));
        mx = fmaxf(mx, __shfl_xor(mx, 8));
        const float mnew = fmaxf(m_i[i], mx);
        const float rs = __expf(m_i[i] - mnew);
        float p0 = __expf(vv[0] - mnew), p1 = __expf(vv[1] - mnew);
        float p2 = __expf(vv[2] - mnew), p3 = __expf(vv[3] - mnew);
        float sum = p0 + p1 + p2 + p3;
        sum += __shfl_xor(sum, 1);
        sum += __shfl_xor(sum, 2);
        sum += __shfl_xor(sum, 4);
        sum += __shfl_xor(sum, 8);
        l_i[i] = l_i[i] * rs + sum;
        m_i[i] = mnew;
        resc[i] = rs;
        unsigned short* prow = &Plds[w][s * 72];
        prow[0 * 16 + lr] = f2bf(p0);
        prow[1 * 16 + lr] = f2bf(p1);
        prow[2 * 16 + lr] = f2bf(p2);
        prow[3 * 16 + lr] = f2bf(p3);
      }
      #pragma unroll
      for (int d8 = 0; d8 < 8; ++d8)
        #pragma unroll
        for (int i = 0; i < 4; ++i) oacc[d8][i] *= resc[i];

      wait_lds();  // Plds[w] is wave-private: DS-retire only

      // ---- PV ----
      #pragma unroll
      for (int ks2 = 0; ks2 < 2; ++ks2) {
        short8 pf = *(const short8*)((char*)&Plds[w][0] + lr * 144 + ks2 * 64 + lc * 16);
        #pragma unroll
        for (int db = 0; db < 8; ++db) {
          const int d = db * 16 + lr;
          const int g = ((d ^ (d >> 3)) & 7) << 4;
          short8 vf = *(const short8*)((char*)&Vt[buf][0] + d * 128 + ((ks2 * 64 + lc * 16) ^ g));
          oacc[db] = __builtin_amdgcn_mfma_f32_16x16x32_bf16(pf, vf, oacc[db], 0, 0, 0);
        }
      }

      bar_lds();                             // B_{t+1}: tile t+1 staged
    }

    // ---- epilogue: partial O, m, l ----
    const size_t pbase = (((size_t)b * NKV + kvh) * ASPLIT + split) * 64;
    #pragma unroll
    for (int db = 0; db < 8; ++db)
      #pragma unroll
      for (int i = 0; i < 4; ++i) {
        const int row = w * 16 + lc * 4 + i;
        Opart[(pbase + row) * HD + db * 16 + lr] = oacc[db][i];
      }
    if (lr == 0) {
      #pragma unroll
      for (int i = 0; i < 4; ++i) {
        const int row = w * 16 + lc * 4 + i;
        ML[(pbase + row) * 2] = m_i[i];
        ML[(pbase + row) * 2 + 1] = l_i[i];
      }
    }
  }
}

// ---------------- combine split-softmax partials -> attn bf16 [64][4096] ----------------
__global__ __launch_bounds__(128) void combine(const float* __restrict__ Opart,
                                               const float* __restrict__ ML,
                                               unsigned short* __restrict__ AT) {
  const int rid = blockIdx.x;
  const int d = threadIdx.x;
  const int s = rid & 15, h = (rid >> 4) & 31, b = rid >> 9;
  const int kvh = h >> 2, g = h & 3;
  const int prow = g * 16 + s;
  const size_t base = ((size_t)b * NKV + kvh) * ASPLIT;
  float ms[ASPLIT], ls[ASPLIT];
  float M = -1e30f;
  #pragma unroll
  for (int sp = 0; sp < ASPLIT; ++sp) {
    ms[sp] = ML[((base + sp) * 64 + prow) * 2];
    ls[sp] = ML[((base + sp) * 64 + prow) * 2 + 1];
    M = fmaxf(M, ms[sp]);
  }
  float denom = 0.f, acc = 0.f;
  #pragma unroll
  for (int sp = 0; sp < ASPLIT; ++sp) {
    const float e = __expf(ms[sp] - M);
    denom += ls[sp] * e;
    acc += e * Opart[((base + sp) * 64 + prow) * HD + d];
  }
  AT[((size_t)(b * 16 + s)) * 4096 + h * 128 + d] = f2bf(acc / denom);
}

// ---------------- reduce Wo partials -> fp32 out ----------------
__global__ __launch_bounds__(256) void wo_reduce(const float* __restrict__ part,
                                                 float* __restrict__ out) {
  const int gid = blockIdx.x * 256 + threadIdx.x;
  float4 s = {0, 0, 0, 0};
  #pragma unroll
  for (int ks = 0; ks < KSPLIT; ++ks) {
    const float4 v = *(const float4*)&part[(size_t)ks * 262144 + (size_t)gid * 4];
    s.x += v.x; s.y += v.y; s.z += v.z; s.w += v.w;
  }
  *(float4*)&out[(size_t)gid * 4] = s;
}

extern "C" void kernel_launch(void* const* d_in, const int* in_sizes, int n_in,
                              void* d_out, int out_size, void* d_ws, size_t ws_size,
                              hipStream_t stream) {
  (void)in_sizes; (void)n_in; (void)out_size; (void)ws_size;
  const float* hs = (const float*)d_in[0];
  const float* kc = (const float*)d_in[1];
  const float* vc = (const float*)d_in[2];
  const float* Wq = (const float*)d_in[3];
  const float* Wk = (const float*)d_in[4];
  const float* Wv = (const float*)d_in[5];
  const float* Wo = (const float*)d_in[6];
  const int* pos = (const int*)d_in[7];
  float* out = (float*)d_out;
  char* ws = (char*)d_ws;

  unsigned short* XB = (unsigned short*)(ws);              // 512 KB
  unsigned short* QR = (unsigned short*)(ws + 0x080000);   // 512 KB
  float* KF = (float*)(ws + 0x100000);                     // 256 KB fp32 new-K
  float* VF = (float*)(ws + 0x140000);                     // 256 KB fp32 new-V
  unsigned short* AT = (unsigned short*)(ws + 0x180000);   // 512 KB
  float* RED = (float*)(ws + 0x200000);                    // gemm partials / Opart (17 MB)
  float* ML  = (float*)(ws + 0x1300000);                   // 256 KB

  hipLaunchKernelGGL(xconv, dim3(256), dim3(256), 0, stream, hs, XB);
  hipLaunchKernelGGL(gemm_skinny, dim3(96, KSPLIT), dim3(256), 0, stream,
                     XB, Wq, Wk, Wv, 4096, 1024, 1024, RED, 6144, 4096 / KSPLIT);
  hipLaunchKernelGGL(proj_reduce, dim3(768), dim3(256), 0, stream, RED, pos, QR, KF, VF);
  hipLaunchKernelGGL(attn_kernel, dim3(NKV * BB, ASPLIT), dim3(512), 0, stream,
                     kc, vc, QR, KF, VF, RED, ML);
  hipLaunchKernelGGL(combine, dim3(2048), dim3(128), 0, stream, RED, ML, AT);
  hipLaunchKernelGGL(gemm_skinny, dim3(64, KSPLIT), dim3(256), 0, stream,
                     AT, Wo, Wo, Wo, 4096, 0, 0, RED, 4096, 4096 / KSPLIT);
  hipLaunchKernelGGL(wo_reduce, dim3(256), dim3(256), 0, stream, RED, out);
}

// Round 11
// 134.058 us; speedup vs baseline: 1.3856x; 1.0068x over previous
//
#include <hip/hip_runtime.h>

#define BB 4
#define SS 16
#define NH 32
#define NKV 8
#define HD 128
#define PAST 8192
#define KVLEN 8208
#define KSPLIT 8
#define ASPLIT 16
#define CHUNK 513   // 16*513 == 8208 exactly
#define NTILE 9

typedef __attribute__((ext_vector_type(8))) short short8;
typedef __attribute__((ext_vector_type(4))) float f32x4;

__device__ __forceinline__ unsigned short f2bf(float f) {
  unsigned u = __float_as_uint(f);
  u = (u + 0x7FFFu + ((u >> 16) & 1u)) >> 16;
  return (unsigned short)u;
}
__device__ __forceinline__ float bf2f(unsigned short h) {
  return __uint_as_float(((unsigned)h) << 16);
}
// packed fp32x2 -> bf16x2 (RNE, identical to f2bf) in one VALU inst
__device__ __forceinline__ unsigned cvtpk(float lo, float hi) {
  unsigned r;
  asm("v_cvt_pk_bf16_f32 %0, %1, %2" : "=v"(r) : "v"(lo), "v"(hi));
  return r;
}
__device__ __forceinline__ void st8(void* p, unsigned lo, unsigned hi) {
  *(unsigned long long*)p = (unsigned long long)lo | ((unsigned long long)hi << 32);
}
__device__ __forceinline__ float getc(const float4& v, int c) {
  return c == 0 ? v.x : c == 1 ? v.y : c == 2 ? v.z : v.w;
}
__device__ __forceinline__ int imin(int a, int b) { return a < b ? a : b; }
__device__ __forceinline__ int imax(int a, int b) { return a > b ? a : b; }

// LDS-ordering barrier that does NOT drain vmcnt.
__device__ __forceinline__ void bar_lds() {
  asm volatile("s_waitcnt lgkmcnt(0)" ::: "memory");
  __builtin_amdgcn_s_barrier();
  asm volatile("" ::: "memory");
}
__device__ __forceinline__ void wait_lds() {
  asm volatile("s_waitcnt lgkmcnt(0)" ::: "memory");
}

// ---------------- hidden_states fp32 -> bf16 ----------------
__global__ __launch_bounds__(256) void xconv(const float* __restrict__ X,
                                             unsigned short* __restrict__ XB) {
  int gid = blockIdx.x * 256 + threadIdx.x;
  float4 v = *(const float4*)&X[(size_t)gid * 4];
  ushort4 pk;
  pk.x = f2bf(v.x); pk.y = f2bf(v.y); pk.z = f2bf(v.z); pk.w = f2bf(v.w);
  *(ushort4*)&XB[(size_t)gid * 4] = pk;
}

// ---------------- skinny GEMM: [64 x K] bf16 @ W(fp32 [K][N]) -> partials ----------------
__global__ __launch_bounds__(256) void gemm_skinny(
    const unsigned short* __restrict__ A,
    const float* __restrict__ W0, const float* __restrict__ W1, const float* __restrict__ W2,
    int nw0, int nw1, int nw2,
    float* __restrict__ part, int Ntot, int kchunk) {
  __shared__ unsigned short Wt[64 * 64];
  const int nt = blockIdx.x, ks = blockIdx.y;
  const int tid = threadIdx.x, lane = tid & 63, w = tid >> 6;
  const int lr = lane & 15, lc = lane >> 4;
  const int n0 = nt * 64;
  const float* W; int wld, wcol;
  if (n0 < nw0) { W = W0; wld = nw0; wcol = n0; }
  else if (n0 < nw0 + nw1) { W = W1; wld = nw1; wcol = n0 - nw0; }
  else { W = W2; wld = nw2; wcol = n0 - nw0 - nw1; }

  f32x4 acc[4];
  #pragma unroll
  for (int mi = 0; mi < 4; ++mi)
    #pragma unroll
    for (int i = 0; i < 4; ++i) acc[mi][i] = 0.f;

  const int qn = tid & 15, qk = tid >> 4;
  const int kb0 = ks * kchunk;
  const int nkt = kchunk / 64;

  float4 wr0, wr1, wr2, wr3;
  {
    const float* wp = &W[(size_t)(kb0 + qk * 4) * wld + wcol + qn * 4];
    wr0 = *(const float4*)(wp);
    wr1 = *(const float4*)(wp + wld);
    wr2 = *(const float4*)(wp + 2 * (size_t)wld);
    wr3 = *(const float4*)(wp + 3 * (size_t)wld);
  }

  for (int kt = 0; kt < nkt; ++kt) {
    const int kb = kb0 + kt * 64;
    #pragma unroll
    for (int c = 0; c < 4; ++c) {
      const int n = qn * 4 + c;
      ushort4 pk;
      pk.x = f2bf(getc(wr0, c)); pk.y = f2bf(getc(wr1, c));
      pk.z = f2bf(getc(wr2, c)); pk.w = f2bf(getc(wr3, c));
      const int byt = n * 128 + ((qk * 8) ^ ((n & 7) << 4));
      *(ushort4*)((char*)Wt + byt) = pk;
    }
    bar_lds();
    if (kt + 1 < nkt) {
      const float* wp = &W[(size_t)(kb + 64 + qk * 4) * wld + wcol + qn * 4];
      wr0 = *(const float4*)(wp);
      wr1 = *(const float4*)(wp + wld);
      wr2 = *(const float4*)(wp + 2 * (size_t)wld);
      wr3 = *(const float4*)(wp + 3 * (size_t)wld);
    }
    #pragma unroll
    for (int kh = 0; kh < 2; ++kh) {
      const int ncol = w * 16 + lr;
      short8 bf = *(const short8*)((char*)Wt + ncol * 128 + ((kh * 64 + lc * 16) ^ ((ncol & 7) << 4)));
      const int kkg = kb + kh * 32 + lc * 8;
      #pragma unroll
      for (int mi = 0; mi < 4; ++mi) {
        short8 af = *(const short8*)&A[(size_t)(mi * 16 + lr) * 4096 + kkg];
        acc[mi] = __builtin_amdgcn_mfma_f32_16x16x32_bf16(af, bf, acc[mi], 0, 0, 0);
      }
    }
    bar_lds();
  }
  #pragma unroll
  for (int mi = 0; mi < 4; ++mi)
    #pragma unroll
    for (int i = 0; i < 4; ++i) {
      const int row = mi * 16 + lc * 4 + i;
      part[((size_t)ks * 64 + row) * Ntot + n0 + w * 16 + lr] = acc[mi][i];
    }
}

// ---------------- reduce proj partials + RoPE -> Qr bf16, K/V-new fp32 ----------------
// exp2(double) is a ~80-cycle libcall; j = tid&63 means every wave recomputes
// the same 64 inv_freq values. Compute the table ONCE per block into LDS
// (64 libcalls instead of 256) -- bit-identical numerics, ~2.7x fewer calls
// grid-wide.
__global__ __launch_bounds__(256) void proj_reduce(
    const float* __restrict__ part, const int* __restrict__ posids,
    unsigned short* __restrict__ QR, float* __restrict__ KF,
    float* __restrict__ VF) {
  __shared__ double sInv[64];
  const int tid = threadIdx.x;
  if (tid < 64)
    sInv[tid] = exp2(-(double)tid * (13.287712379549449 / 64.0)); // 10000^(-j/64)
  __syncthreads();

  const int gid = blockIdx.x * 256 + tid;
  const int j = gid & 63;
  const int hh = (gid >> 6) % 48;
  const int row = gid / 3072;
  const int b = row >> 4, s = row & 15;
  int col0; bool rope;
  if (hh < 32)      { col0 = hh * 128 + j; rope = true; }
  else if (hh < 40) { col0 = 4096 + (hh - 32) * 128 + j; rope = true; }
  else              { col0 = 5120 + (hh - 40) * 128 + j; rope = false; }
  float v0 = 0.f, v1 = 0.f;
  #pragma unroll
  for (int ks = 0; ks < KSPLIT; ++ks) {
    v0 += part[((size_t)ks * 64 + row) * 6144 + col0];
    v1 += part[((size_t)ks * 64 + row) * 6144 + col0 + 64];
  }
  float o0 = v0, o1 = v1;
  if (rope) {
    const int pos = posids[row];
    const double inv = sInv[j];
    double th = (double)pos * inv;
    const double TWO_PI = 6.283185307179586476925286766559;
    th -= floor(th / TWO_PI) * TWO_PI;
    float sv, cv;
    sincosf((float)th, &sv, &cv);
    o0 = v0 * cv - v1 * sv;
    o1 = v1 * cv + v0 * sv;
  }
  if (hh < 32) {
    const size_t didx = (((size_t)(b * 32 + hh) * 16 + s) * 128) + j;
    QR[didx] = f2bf(o0);
    QR[didx + 64] = f2bf(o1);
  } else if (hh < 40) {
    const size_t didx = (((size_t)(b * 8 + (hh - 32)) * 16 + s) * 128) + j;
    KF[didx] = o0;
    KF[didx + 64] = o1;
  } else {
    const size_t didx = (((size_t)(b * 8 + (hh - 40)) * 16 + s) * 128) + j;
    VF[didx] = o0;
    VF[didx + 64] = o1;
  }
}

// ---------------- flash attention: wave-specialized producer/consumer ----------------
// FROZEN at R10 (best measured): byte-identical body. Reads the irreducible
// 268 MB KV at the replicated supply ceiling (~3.25 TB/s combined HBM+L3,
// invariant across 6 schedule variants R2..R10).
__global__ __launch_bounds__(512, 2) void attn_kernel(
    const float* __restrict__ kc, const float* __restrict__ vc,
    const unsigned short* __restrict__ QR, const float* __restrict__ KF,
    const float* __restrict__ VF,
    float* __restrict__ Opart, float* __restrict__ ML) {
  __shared__ unsigned short Klds[2][64 * 136];  // [key][128d], row 272B (pad 8)
  __shared__ unsigned short Vt[2][128 * 64];    // [d][64key], XOR swizzle g(d)
  __shared__ unsigned short Plds[4][16 * 72];   // per-consumer-wave P

  const int kvh = blockIdx.x & 7, b = blockIdx.x >> 3;  // 32 consecutive blocks
  const int split = blockIdx.y;                         // share one key range
  const int tid = threadIdx.x;
  const int kstart = split * CHUNK;

  if (tid >= 256) {
    // ================= PRODUCER: 4 waves stage K/V tiles =================
    const int ptid = tid - 256;
    const int dl = (ptid & 31) * 4;   // d-offset (floats)
    const int rk = ptid >> 5;         // row-group 0..7
    const float* kc_base = kc + (((size_t)b * PAST) * NKV + kvh) * HD + dl;
    const float* vc_base = vc + (((size_t)b * PAST) * NKV + kvh) * HD + dl;
    const float* kf_base = KF + (((size_t)b * NKV + kvh) * SS) * HD + dl;
    const float* vf_base = VF + (((size_t)b * NKV + kvh) * SS) * HD + dl;

    auto stage = [&](int kk0, int buf) {
      float4 kpre[8];   // K rows pass*8+rk
      float4 vpre[8];   // V rows rk*8+j
      #pragma unroll
      for (int pass = 0; pass < 8; ++pass) {
        const int kk = kk0 + pass * 8 + rk;
        const int ts = imin(imax(kk - PAST, 0), SS - 1);
        const float* p = (kk < PAST) ? (kc_base + (size_t)kk * (NKV * HD))
                                     : (kf_base + (size_t)ts * HD);
        kpre[pass] = *(const float4*)p;
      }
      #pragma unroll
      for (int j = 0; j < 8; ++j) {
        const int kk = kk0 + rk * 8 + j;
        const int ts = imin(imax(kk - PAST, 0), SS - 1);
        const float* p = (kk < PAST) ? (vc_base + (size_t)kk * (NKV * HD))
                                     : (vf_base + (size_t)ts * HD);
        vpre[j] = *(const float4*)p;
      }
      #pragma unroll
      for (int pass = 0; pass < 8; ++pass) {
        const int kr = pass * 8 + rk;
        st8((char*)&Klds[buf][0] + kr * 272 + dl * 2,
            cvtpk(kpre[pass].x, kpre[pass].y), cvtpk(kpre[pass].z, kpre[pass].w));
      }
      #pragma unroll
      for (int pp = 0; pp < 2; ++pp) {
        const int krb = rk * 8 + pp * 4;
        #pragma unroll
        for (int c = 0; c < 4; ++c) {
          const int d = dl + c;
          const int g = ((d ^ (d >> 3)) & 7) << 4;
          st8((char*)&Vt[buf][0] + d * 128 + ((krb * 2) ^ g),
              cvtpk(getc(vpre[pp * 4 + 0], c), getc(vpre[pp * 4 + 1], c)),
              cvtpk(getc(vpre[pp * 4 + 2], c), getc(vpre[pp * 4 + 3], c)));
        }
      }
    };

    stage(kstart, 0);
    bar_lds();                               // B0: tile 0 ready
    for (int t = 0; t < NTILE; ++t) {
      if (t + 1 < NTILE) stage(kstart + (t + 1) * 64, (t + 1) & 1);
      bar_lds();                             // B_{t+1}
    }
    // producers exit; no barriers after this point anywhere
  } else {
    // ================= CONSUMER: 4 waves, one head each =================
    const int lane = tid & 63, w = tid >> 6;
    const int lr = lane & 15, lc = lane >> 4;

    short8 qf[4];
    {
      const unsigned short* qb = QR + (((size_t)b * NH + kvh * 4 + w) * SS + lr) * HD;
      #pragma unroll
      for (int kd = 0; kd < 4; ++kd) qf[kd] = *(const short8*)(qb + kd * 32 + lc * 8);
    }

    float m_i[4], l_i[4];
    f32x4 oacc[8];
    #pragma unroll
    for (int i = 0; i < 4; ++i) { m_i[i] = -1e30f; l_i[i] = 0.f; }
    #pragma unroll
    for (int d8 = 0; d8 < 8; ++d8)
      #pragma unroll
      for (int i = 0; i < 4; ++i) oacc[d8][i] = 0.f;

    bar_lds();                               // B0: wait tile 0

    for (int t = 0; t < NTILE; ++t) {
      const int buf = t & 1;
      const int kk0 = kstart + t * 64;
      const int nvalid = imin(64, kstart + CHUNK - kk0);

      // ---- QK^T ----
      f32x4 sacc[4];
      #pragma unroll
      for (int nb = 0; nb < 4; ++nb)
        #pragma unroll
        for (int i = 0; i < 4; ++i) sacc[nb][i] = 0.f;
      #pragma unroll
      for (int kd = 0; kd < 4; ++kd) {
        #pragma unroll
        for (int nb = 0; nb < 4; ++nb) {
          const int key = nb * 16 + lr;
          short8 bf = *(const short8*)((char*)&Klds[buf][0] + key * 272 + kd * 64 + lc * 16);
          sacc[nb] = __builtin_amdgcn_mfma_f32_16x16x32_bf16(qf[kd], bf, sacc[nb], 0, 0, 0);
        }
      }

      // ---- online softmax (row s = lc*4+i, key col = nb*16+lr) ----
      const float scl = 0.08838834764831845f;
      float resc[4];
      #pragma unroll
      for (int i = 0; i < 4; ++i) {
        const int s = lc * 4 + i;
        float vv[4];
        #pragma unroll
        for (int nb = 0; nb < 4; ++nb) {
          const int klocal = nb * 16 + lr;
          const int kk = kk0 + klocal;
          const bool ok = (klocal < nvalid) && (kk <= PAST + s);
          vv[nb] = ok ? sacc[nb][i] * scl : -1e30f;
        }
        float mx = fmaxf(fmaxf(vv[0], vv[1]), fmaxf(vv[2], vv[3]));
        mx = fmaxf(mx, __shfl_xor(mx, 1));
        mx = fmaxf(mx, __shfl_xor(mx, 2));
        mx = fmaxf(mx, __shfl_xor(mx, 4));
        mx = fmaxf(mx, __shfl_xor(mx, 8));
        const float mnew = fmaxf(m_i[i], mx);
        const float rs = __expf(m_i[i] - mnew);
        float p0 = __expf(vv[0] - mnew), p1 = __expf(vv[1] - mnew);
        float p2 = __expf(vv[2] - mnew), p3 = __expf(vv[3] - mnew);
        float sum = p0 + p1 + p2 + p3;
        sum += __shfl_xor(sum, 1);
        sum += __shfl_xor(sum, 2);
        sum += __shfl_xor(sum, 4);
        sum += __shfl_xor(sum, 8);
        l_i[i] = l_i[i] * rs + sum;
        m_i[i] = mnew;
        resc[i] = rs;
        unsigned short* prow = &Plds[w][s * 72];
        prow[0 * 16 + lr] = f2bf(p0);
        prow[1 * 16 + lr] = f2bf(p1);
        prow[2 * 16 + lr] = f2bf(p2);
        prow[3 * 16 + lr] = f2bf(p3);
      }
      #pragma unroll
      for (int d8 = 0; d8 < 8; ++d8)
        #pragma unroll
        for (int i = 0; i < 4; ++i) oacc[d8][i] *= resc[i];

      wait_lds();  // Plds[w] is wave-private: DS-retire only

      // ---- PV ----
      #pragma unroll
      for (int ks2 = 0; ks2 < 2; ++ks2) {
        short8 pf = *(const short8*)((char*)&Plds[w][0] + lr * 144 + ks2 * 64 + lc * 16);
        #pragma unroll
        for (int db = 0; db < 8; ++db) {
          const int d = db * 16 + lr;
          const int g = ((d ^ (d >> 3)) & 7) << 4;
          short8 vf = *(const short8*)((char*)&Vt[buf][0] + d * 128 + ((ks2 * 64 + lc * 16) ^ g));
          oacc[db] = __builtin_amdgcn_mfma_f32_16x16x32_bf16(pf, vf, oacc[db], 0, 0, 0);
        }
      }

      bar_lds();                             // B_{t+1}: tile t+1 staged
    }

    // ---- epilogue: partial O, m, l ----
    const size_t pbase = (((size_t)b * NKV + kvh) * ASPLIT + split) * 64;
    #pragma unroll
    for (int db = 0; db < 8; ++db)
      #pragma unroll
      for (int i = 0; i < 4; ++i) {
        const int row = w * 16 + lc * 4 + i;
        Opart[(pbase + row) * HD + db * 16 + lr] = oacc[db][i];
      }
    if (lr == 0) {
      #pragma unroll
      for (int i = 0; i < 4; ++i) {
        const int row = w * 16 + lc * 4 + i;
        ML[(pbase + row) * 2] = m_i[i];
        ML[(pbase + row) * 2 + 1] = l_i[i];
      }
    }
  }
}

// ---------------- combine split-softmax partials -> attn bf16 [64][4096] ----------------
__global__ __launch_bounds__(128) void combine(const float* __restrict__ Opart,
                                               const float* __restrict__ ML,
                                               unsigned short* __restrict__ AT) {
  const int rid = blockIdx.x;
  const int d = threadIdx.x;
  const int s = rid & 15, h = (rid >> 4) & 31, b = rid >> 9;
  const int kvh = h >> 2, g = h & 3;
  const int prow = g * 16 + s;
  const size_t base = ((size_t)b * NKV + kvh) * ASPLIT;
  float ms[ASPLIT], ls[ASPLIT];
  float M = -1e30f;
  #pragma unroll
  for (int sp = 0; sp < ASPLIT; ++sp) {
    ms[sp] = ML[((base + sp) * 64 + prow) * 2];
    ls[sp] = ML[((base + sp) * 64 + prow) * 2 + 1];
    M = fmaxf(M, ms[sp]);
  }
  float denom = 0.f, acc = 0.f;
  #pragma unroll
  for (int sp = 0; sp < ASPLIT; ++sp) {
    const float e = __expf(ms[sp] - M);
    denom += ls[sp] * e;
    acc += e * Opart[((base + sp) * 64 + prow) * HD + d];
  }
  AT[((size_t)(b * 16 + s)) * 4096 + h * 128 + d] = f2bf(acc / denom);
}

// ---------------- reduce Wo partials -> fp32 out ----------------
__global__ __launch_bounds__(256) void wo_reduce(const float* __restrict__ part,
                                                 float* __restrict__ out) {
  const int gid = blockIdx.x * 256 + threadIdx.x;
  float4 s = {0, 0, 0, 0};
  #pragma unroll
  for (int ks = 0; ks < KSPLIT; ++ks) {
    const float4 v = *(const float4*)&part[(size_t)ks * 262144 + (size_t)gid * 4];
    s.x += v.x; s.y += v.y; s.z += v.z; s.w += v.w;
  }
  *(float4*)&out[(size_t)gid * 4] = s;
}

extern "C" void kernel_launch(void* const* d_in, const int* in_sizes, int n_in,
                              void* d_out, int out_size, void* d_ws, size_t ws_size,
                              hipStream_t stream) {
  (void)in_sizes; (void)n_in; (void)out_size; (void)ws_size;
  const float* hs = (const float*)d_in[0];
  const float* kc = (const float*)d_in[1];
  const float* vc = (const float*)d_in[2];
  const float* Wq = (const float*)d_in[3];
  const float* Wk = (const float*)d_in[4];
  const float* Wv = (const float*)d_in[5];
  const float* Wo = (const float*)d_in[6];
  const int* pos = (const int*)d_in[7];
  float* out = (float*)d_out;
  char* ws = (char*)d_ws;

  unsigned short* XB = (unsigned short*)(ws);              // 512 KB
  unsigned short* QR = (unsigned short*)(ws + 0x080000);   // 512 KB
  float* KF = (float*)(ws + 0x100000);                     // 256 KB fp32 new-K
  float* VF = (float*)(ws + 0x140000);                     // 256 KB fp32 new-V
  unsigned short* AT = (unsigned short*)(ws + 0x180000);   // 512 KB
  float* RED = (float*)(ws + 0x200000);                    // gemm partials / Opart (17 MB)
  float* ML  = (float*)(ws + 0x1300000);                   // 256 KB

  hipLaunchKernelGGL(xconv, dim3(256), dim3(256), 0, stream, hs, XB);
  hipLaunchKernelGGL(gemm_skinny, dim3(96, KSPLIT), dim3(256), 0, stream,
                     XB, Wq, Wk, Wv, 4096, 1024, 1024, RED, 6144, 4096 / KSPLIT);
  hipLaunchKernelGGL(proj_reduce, dim3(768), dim3(256), 0, stream, RED, pos, QR, KF, VF);
  hipLaunchKernelGGL(attn_kernel, dim3(NKV * BB, ASPLIT), dim3(512), 0, stream,
                     kc, vc, QR, KF, VF, RED, ML);
  hipLaunchKernelGGL(combine, dim3(2048), dim3(128), 0, stream, RED, ML, AT);
  hipLaunchKernelGGL(gemm_skinny, dim3(64, KSPLIT), dim3(256), 0, stream,
                     AT, Wo, Wo, Wo, 4096, 0, 0, RED, 4096, 4096 / KSPLIT);
  hipLaunchKernelGGL(wo_reduce, dim3(256), dim3(256), 0, stream, RED, out);
}